// Round 1
// baseline (475.519 us; speedup 1.0000x reference)
//
#include <hip/hip_runtime.h>
#include <math.h>

#define NEG 0.2f

// ---------------------------------------------------------------------------
// CSR build: histogram -> single-block exclusive scan -> scatter
// ---------------------------------------------------------------------------
__global__ void k_hist(const int* __restrict__ dst, int E, int* __restrict__ deg) {
    int i = blockIdx.x * 256 + threadIdx.x;
    if (i < E) atomicAdd(&deg[dst[i]], 1);
}

// grid=2: block 0 scans a (len na) in place, block 1 scans b (len nb).
__global__ __launch_bounds__(1024) void k_scan2(int* a, int na, int* b, int nb) {
    int* p = (blockIdx.x == 0) ? a : b;
    int n  = (blockIdx.x == 0) ? na : nb;
    __shared__ int sums[1024];
    int t = threadIdx.x;
    int C = (n + 1023) >> 10;
    int base = t * C;
    int s = 0;
    for (int j = 0; j < C; ++j) { int i = base + j; if (i < n) s += p[i]; }
    sums[t] = s;
    __syncthreads();
    for (int off = 1; off < 1024; off <<= 1) {
        int v = (t >= off) ? sums[t - off] : 0;
        __syncthreads();
        sums[t] += v;
        __syncthreads();
    }
    int run = (t == 0) ? 0 : sums[t - 1];
    for (int j = 0; j < C; ++j) {
        int i = base + j;
        if (i < n) { int v = p[i]; p[i] = run; run += v; }
    }
}

__global__ void k_scatter(const int* __restrict__ src, const int* __restrict__ dst,
                          int E, int* __restrict__ cur, int* __restrict__ csr) {
    int i = blockIdx.x * 256 + threadIdx.x;
    if (i < E) {
        int d = dst[i];
        int pos = atomicAdd(&cur[d], 1);
        csr[pos] = src[i];
    }
}

// ---------------------------------------------------------------------------
// GATv2 layer: one wave per dst node; lane owns 4 contiguous dims of 256
// (lane*4 .. lane*4+3), so lanes 16h..16h+15 form head h. fs computed on the
// fly from x_src[s][0..7] and register-resident Ws slice. Online softmax.
// ---------------------------------------------------------------------------
__global__ __launch_bounds__(256) void k_gat(
    const float* __restrict__ x_src, const float* __restrict__ x_dst,
    const int* __restrict__ pfx, const int* __restrict__ csr,
    const float* __restrict__ Ws, const float* __restrict__ bs,
    const float* __restrict__ Wd, const float* __restrict__ bd,
    const float* __restrict__ attn,
    const float* __restrict__ Wr, const float* __restrict__ br,
    float* __restrict__ xcat, int n_dst, int col_off)
{
    __shared__ __align__(16) float sWd[16 * 256];
    __shared__ __align__(16) float sWr[16 * 256];
    __shared__ __align__(16) float sWs[8 * 256];
    __shared__ __align__(16) float sB[4 * 256];   // bs | bd | br | attn

    int t = threadIdx.x;
#pragma unroll
    for (int i = 0; i < 4; ++i)
        ((float4*)sWd)[t + i * 256] = ((const float4*)Wd)[t + i * 256];
#pragma unroll
    for (int i = 0; i < 4; ++i)
        ((float4*)sWr)[t + i * 256] = ((const float4*)Wr)[t + i * 256];
#pragma unroll
    for (int i = 0; i < 2; ++i)
        ((float4*)sWs)[t + i * 256] = ((const float4*)Ws)[t + i * 256];
    if (t < 64)       ((float4*)(sB      ))[t      ] = ((const float4*)bs  )[t      ];
    else if (t < 128) ((float4*)(sB + 256))[t - 64 ] = ((const float4*)bd  )[t - 64 ];
    else if (t < 192) ((float4*)(sB + 512))[t - 128] = ((const float4*)br  )[t - 128];
    else              ((float4*)(sB + 768))[t - 192] = ((const float4*)attn)[t - 192];
    __syncthreads();

    int wave = t >> 6, lane = t & 63;
    int node = blockIdx.x * 4 + wave;
    if (node >= n_dst) return;
    int dim0 = lane << 2;

    // per-lane constants
    float ws_r[8][4];
#pragma unroll
    for (int k = 0; k < 8; ++k) {
        float4 w = *(const float4*)&sWs[k * 256 + dim0];
        ws_r[k][0] = w.x; ws_r[k][1] = w.y; ws_r[k][2] = w.z; ws_r[k][3] = w.w;
    }
    float4 bsv = *(const float4*)&sB[dim0];
    float4 atv = *(const float4*)&sB[768 + dim0];

    // fd = x_dst@Wd + bd, fr = x_dst@Wr + br (this node's 4 dims per lane)
    float fd0, fd1, fd2, fd3, fr0, fr1, fr2, fr3;
    {
        float4 bdv = *(const float4*)&sB[256 + dim0];
        float4 brv = *(const float4*)&sB[512 + dim0];
        fd0 = bdv.x; fd1 = bdv.y; fd2 = bdv.z; fd3 = bdv.w;
        fr0 = brv.x; fr1 = brv.y; fr2 = brv.z; fr3 = brv.w;
    }
    const float* xrow = x_dst + (size_t)node * 16;
#pragma unroll
    for (int q = 0; q < 4; ++q) {
        float4 xv = *(const float4*)&xrow[q * 4];
#pragma unroll
        for (int kk = 0; kk < 4; ++kk) {
            int k = q * 4 + kk;
            float xk = (kk == 0) ? xv.x : (kk == 1) ? xv.y : (kk == 2) ? xv.z : xv.w;
            float4 wd = *(const float4*)&sWd[k * 256 + dim0];
            float4 wr = *(const float4*)&sWr[k * 256 + dim0];
            fd0 = fmaf(xk, wd.x, fd0); fd1 = fmaf(xk, wd.y, fd1);
            fd2 = fmaf(xk, wd.z, fd2); fd3 = fmaf(xk, wd.w, fd3);
            fr0 = fmaf(xk, wr.x, fr0); fr1 = fmaf(xk, wr.y, fr1);
            fr2 = fmaf(xk, wr.z, fr2); fr3 = fmaf(xk, wr.w, fr3);
        }
    }

    int start = (node == 0) ? 0 : pfx[node - 1];
    int end = pfx[node];

    float m = -INFINITY, l = 0.f;
    float acc0 = 0.f, acc1 = 0.f, acc2 = 0.f, acc3 = 0.f;

    // 2-deep software pipeline over edges
    int sA = (start < end) ? csr[start] : 0;
    int sB2 = (start + 1 < end) ? csr[start + 1] : 0;
    float4 fA0 = *(const float4*)&x_src[(size_t)sA * 8];
    float4 fA1 = *(const float4*)&x_src[(size_t)sA * 8 + 4];
    for (int e = start; e < end; ++e) {
        float4 gB0 = *(const float4*)&x_src[(size_t)sB2 * 8];
        float4 gB1 = *(const float4*)&x_src[(size_t)sB2 * 8 + 4];
        int sC = (e + 2 < end) ? csr[e + 2] : 0;

        float fs0 = bsv.x, fs1 = bsv.y, fs2 = bsv.z, fs3 = bsv.w;
#define FSK(val, k) \
        fs0 = fmaf(val, ws_r[k][0], fs0); \
        fs1 = fmaf(val, ws_r[k][1], fs1); \
        fs2 = fmaf(val, ws_r[k][2], fs2); \
        fs3 = fmaf(val, ws_r[k][3], fs3);
        FSK(fA0.x, 0) FSK(fA0.y, 1) FSK(fA0.z, 2) FSK(fA0.w, 3)
        FSK(fA1.x, 4) FSK(fA1.y, 5) FSK(fA1.z, 6) FSK(fA1.w, 7)
#undef FSK

        float t0 = fs0 + fd0; t0 = (t0 > 0.f) ? t0 : NEG * t0;
        float t1 = fs1 + fd1; t1 = (t1 > 0.f) ? t1 : NEG * t1;
        float t2 = fs2 + fd2; t2 = (t2 > 0.f) ? t2 : NEG * t2;
        float t3 = fs3 + fd3; t3 = (t3 > 0.f) ? t3 : NEG * t3;
        float sc = t0 * atv.x;
        sc = fmaf(t1, atv.y, sc);
        sc = fmaf(t2, atv.z, sc);
        sc = fmaf(t3, atv.w, sc);
        // reduce across the 16 lanes of this head (all lanes get the sum)
        sc += __shfl_xor(sc, 1, 16);
        sc += __shfl_xor(sc, 2, 16);
        sc += __shfl_xor(sc, 4, 16);
        sc += __shfl_xor(sc, 8, 16);

        float mn = fmaxf(m, sc);
        float corr = __expf(m - mn);    // 0 on first edge (m = -inf)
        float p = __expf(sc - mn);
        l = fmaf(l, corr, p);
        acc0 = fmaf(acc0, corr, p * fs0);
        acc1 = fmaf(acc1, corr, p * fs1);
        acc2 = fmaf(acc2, corr, p * fs2);
        acc3 = fmaf(acc3, corr, p * fs3);
        m = mn;

        fA0 = gB0; fA1 = gB1; sB2 = sC;
    }

    float inv = (l > 0.f) ? 1.f / l : 0.f;   // zero in-degree -> rst = 0
    float4 o;
    o.x = fmaxf(fmaf(acc0, inv, fr0), 0.f);
    o.y = fmaxf(fmaf(acc1, inv, fr1), 0.f);
    o.z = fmaxf(fmaf(acc2, inv, fr2), 0.f);
    o.w = fmaxf(fmaf(acc3, inv, fr3), 0.f);
    *(float4*)&xcat[(size_t)node * 512 + col_off + dim0] = o;
}

// ---------------------------------------------------------------------------
// out = relu(X[M,512] @ W[512,256] + b). f32 vector GEMM, KT=32 LDS tiles.
// Block: 256 threads, 16 rows x 256 cols; thread = 4 rows x 4 cols.
// ---------------------------------------------------------------------------
#define KT 32
__global__ __launch_bounds__(256) void k_mlp(
    const float* __restrict__ X, const float* __restrict__ W,
    const float* __restrict__ b, float* __restrict__ out, int M)
{
    __shared__ __align__(16) float sW[KT * 256];   // 32 KB
    __shared__ __align__(16) float sX[16 * KT];    // 2 KB
    int t = threadIdx.x;
    int rbase = blockIdx.x * 16;
    int col_q = t & 63;   // cols col_q*4 .. +3
    int row_q = t >> 6;   // rows row_q*4 .. +3 (within 16-row tile)
    float acc[4][4] = {};

    for (int k0 = 0; k0 < 512; k0 += KT) {
        __syncthreads();
        // stage W tile: KT*256 floats = 2048 float4, 8 per thread
#pragma unroll
        for (int i = 0; i < 8; ++i) {
            int idx = t + i * 256;
            ((float4*)sW)[idx] = ((const float4*)(W + k0 * 256))[idx];
        }
        // stage X tile: 16 rows x KT = 128 float4, threads 0..127
        if (t < 128) {
            int r = t >> 3;        // 0..15
            int q = t & 7;         // cols q*4
            int row = rbase + r;
            float4 v = (row < M) ? *(const float4*)&X[(size_t)row * 512 + k0 + q * 4]
                                 : make_float4(0.f, 0.f, 0.f, 0.f);
            *(float4*)&sX[r * KT + q * 4] = v;
        }
        __syncthreads();
#pragma unroll 4
        for (int k = 0; k < KT; ++k) {
            float4 w = *(const float4*)&sW[k * 256 + col_q * 4];
#pragma unroll
            for (int r = 0; r < 4; ++r) {
                float x = sX[(row_q * 4 + r) * KT + k];
                acc[r][0] = fmaf(x, w.x, acc[r][0]);
                acc[r][1] = fmaf(x, w.y, acc[r][1]);
                acc[r][2] = fmaf(x, w.z, acc[r][2]);
                acc[r][3] = fmaf(x, w.w, acc[r][3]);
            }
        }
    }
    float4 bias = *(const float4*)&b[col_q * 4];
#pragma unroll
    for (int r = 0; r < 4; ++r) {
        int row = rbase + row_q * 4 + r;
        if (row < M) {
            float4 o;
            o.x = fmaxf(acc[r][0] + bias.x, 0.f);
            o.y = fmaxf(acc[r][1] + bias.y, 0.f);
            o.z = fmaxf(acc[r][2] + bias.z, 0.f);
            o.w = fmaxf(acc[r][3] + bias.w, 0.f);
            *(float4*)&out[(size_t)row * 256 + col_q * 4] = o;
        }
    }
}

// ---------------------------------------------------------------------------
extern "C" void kernel_launch(void* const* d_in, const int* in_sizes, int n_in,
                              void* d_out, int out_size, void* d_ws, size_t ws_size,
                              hipStream_t stream) {
    const float* x_gt   = (const float*)d_in[0];
    const float* x_ubs  = (const float*)d_in[1];
    const float* x_ag   = (const float*)d_in[2];
    const int* seen_src = (const int*)d_in[3];
    const int* seen_dst = (const int*)d_in[4];
    const int* near_src = (const int*)d_in[5];
    const int* near_dst = (const int*)d_in[6];
    const float* Ws_s = (const float*)d_in[7];  const float* bs_s = (const float*)d_in[8];
    const float* Wd_s = (const float*)d_in[9];  const float* bd_s = (const float*)d_in[10];
    const float* at_s = (const float*)d_in[11];
    const float* Wr_s = (const float*)d_in[12]; const float* br_s = (const float*)d_in[13];
    const float* Ws_n = (const float*)d_in[14]; const float* bs_n = (const float*)d_in[15];
    const float* Wd_n = (const float*)d_in[16]; const float* bd_n = (const float*)d_in[17];
    const float* at_n = (const float*)d_in[18];
    const float* Wr_n = (const float*)d_in[19]; const float* br_n = (const float*)d_in[20];
    const float* W_a  = (const float*)d_in[21]; const float* b_a  = (const float*)d_in[22];

    const int n_ag = in_sizes[2] / 16;
    const int E_s  = in_sizes[3];
    const int E_n  = in_sizes[5];

    char* ws = (char*)d_ws;
    int* cur_s = (int*)ws;  ws += (size_t)n_ag * 4;
    int* cur_n = (int*)ws;  ws += (size_t)n_ag * 4;
    int* csr_s = (int*)ws;  ws += (size_t)E_s * 4;
    int* csr_n = (int*)ws;  ws += (size_t)E_n * 4;
    float* xcat = (float*)ws;   // [n_ag, 512]

    hipMemsetAsync(cur_s, 0, (size_t)n_ag * 8, stream);  // cur_s and cur_n contiguous

    k_hist<<<(E_s + 255) / 256, 256, 0, stream>>>(seen_dst, E_s, cur_s);
    k_hist<<<(E_n + 255) / 256, 256, 0, stream>>>(near_dst, E_n, cur_n);
    k_scan2<<<2, 1024, 0, stream>>>(cur_s, n_ag, cur_n, n_ag);
    k_scatter<<<(E_s + 255) / 256, 256, 0, stream>>>(seen_src, seen_dst, E_s, cur_s, csr_s);
    k_scatter<<<(E_n + 255) / 256, 256, 0, stream>>>(near_src, near_dst, E_n, cur_n, csr_n);

    k_gat<<<(n_ag + 3) / 4, 256, 0, stream>>>(x_gt, x_ag, cur_s, csr_s,
        Ws_s, bs_s, Wd_s, bd_s, at_s, Wr_s, br_s, xcat, n_ag, 0);
    k_gat<<<(n_ag + 3) / 4, 256, 0, stream>>>(x_ubs, x_ag, cur_n, csr_n,
        Ws_n, bs_n, Wd_n, bd_n, at_n, Wr_n, br_n, xcat, n_ag, 256);

    k_mlp<<<(n_ag + 15) / 16, 256, 0, stream>>>(xcat, W_a, b_a, (float*)d_out, n_ag);
}